// Round 14
// baseline (29.034 us; speedup 1.0000x reference)
//
#include <hip/hip_runtime.h>
#include <math.h>

// ---------------------------------------------------------------------------
// FraudDetectionHybrid: 4-qubit statevector sim, algebraically collapsed.
// R14 = R12 (best, 22.6us) + K_B LAUNCHED TWICE as a pure MEASUREMENT round:
//   K_B is idempotent -> correctness unchanged; dur_new - 22.6 = K_B's true
//   duration. Decides whether the next rewrite targets K_B (matvec) or
//   K_A/fixed overhead. (Profiler top-5 shows only 40us harness fills, so
//   kernel-level timing is otherwise invisible.)
//
// History: R1-R3 scratch pathologies (constexpr gates+templates). R4 dispatch
// ~0.5us. R5-R8 grid barriers lose to dispatch boundaries. R9/R10 native trig
// + s_load-uniform U. R11/R13: TLP splits null — waves/SIMD=2 is fixed by
// B/64/1024; extra TLP costs duplicated phase1. R12: pk matvec −1.6us.
// ---------------------------------------------------------------------------

// ==================== compile-time numpy RandomState(42) ====================
struct CGates {
  int kind[64];   // 0=RX 1=RY 2=RZ 3=CNOT 4=CRX 5=H 6=SX
  int w0[64];
  int w1[64];
  int pidx[64];   // >=0: rand_params idx; -1 none; -2 rx0; -3 ry0; -4 rz0; -5 crx0
  int ng;
};

constexpr unsigned int c_mt_next(unsigned int (&mt)[624], int& pos) {
  if (pos >= 624) {
    for (int i = 0; i < 624; ++i) {
      unsigned int y = (mt[i] & 0x80000000u) | (mt[(i + 1) % 624] & 0x7fffffffu);
      unsigned int v = mt[(i + 397) % 624] ^ (y >> 1);
      if (y & 1u) v ^= 0x9908b0dfu;
      mt[i] = v;
    }
    pos = 0;
  }
  unsigned int y = mt[pos++];
  y ^= y >> 11;
  y ^= (y << 7) & 0x9d2c5680u;
  y ^= (y << 15) & 0xefc60000u;
  y ^= y >> 18;
  return y;
}

constexpr CGates make_gates() {
  CGates gl{};
  unsigned int mt[624] = {};
  mt[0] = 42u;
  for (int i = 1; i < 624; ++i)
    mt[i] = 1812433253u * (mt[i - 1] ^ (mt[i - 1] >> 30)) + (unsigned int)i;
  int pos = 624;
  int ng = 0, p = 0;
  for (int op = 0; op < 50; ++op) {
    unsigned int k = c_mt_next(mt, pos) & 3u;   // randint(4): one draw, mask 3
    if (k < 3u) {
      unsigned int w = c_mt_next(mt, pos) & 3u; // wire
      gl.kind[ng] = (int)k; gl.w0[ng] = (int)w; gl.w1[ng] = 0;
      gl.pidx[ng] = p++;
      ++ng;
    } else {
      // choice(4,2,replace=False): Fisher-Yates descending, mask-rejection
      int arr[4] = {0, 1, 2, 3};
      { unsigned int j = c_mt_next(mt, pos) & 3u;
        int t = arr[3]; arr[3] = arr[j]; arr[j] = t; }
      { unsigned int j = c_mt_next(mt, pos) & 3u;
        while (j > 2u) j = c_mt_next(mt, pos) & 3u;
        int t = arr[2]; arr[2] = arr[j]; arr[j] = t; }
      { unsigned int j = c_mt_next(mt, pos) & 1u;
        int t = arr[1]; arr[1] = arr[j]; arr[j] = t; }
      gl.kind[ng] = 3; gl.w0[ng] = arr[0]; gl.w1[ng] = arr[1]; gl.pidx[ng] = -1;
      ++ng;
    }
  }
  // trainable block
  gl.kind[ng] = 0; gl.w0[ng] = 0; gl.w1[ng] = 0; gl.pidx[ng] = -2; ++ng; // RX w0
  gl.kind[ng] = 1; gl.w0[ng] = 1; gl.w1[ng] = 0; gl.pidx[ng] = -3; ++ng; // RY w1
  gl.kind[ng] = 2; gl.w0[ng] = 3; gl.w1[ng] = 0; gl.pidx[ng] = -4; ++ng; // RZ w3
  gl.kind[ng] = 4; gl.w0[ng] = 0; gl.w1[ng] = 2; gl.pidx[ng] = -5; ++ng; // CRX(0,2)
  gl.kind[ng] = 5; gl.w0[ng] = 3; gl.w1[ng] = 0; gl.pidx[ng] = -1; ++ng; // H w3
  gl.kind[ng] = 6; gl.w0[ng] = 2; gl.w1[ng] = 0; gl.pidx[ng] = -1; ++ng; // SX w2
  gl.kind[ng] = 3; gl.w0[ng] = 3; gl.w1[ng] = 0; gl.pidx[ng] = -1; ++ng; // CNOT(3,0)
  gl.ng = ng;
  return gl;
}

inline constexpr CGates GL = make_gates();

inline constexpr int CK1 = GL.ng / 4;
inline constexpr int CK2 = GL.ng / 2;
inline constexpr int CK3 = (3 * GL.ng) / 4;

// ================= templated gate appliers (static indices) =================
// wire0 = MSB (bit 3): TB = 8 >> wire.

template <int TB>
__device__ __forceinline__ void ap_rx(float (&sx)[16], float (&sy)[16],
                                      float c, float s) {
#pragma unroll
  for (int i = 0; i < 16; ++i) {
    if (i & TB) continue;
    const int j = i | TB;
    float ax = sx[i], ay = sy[i], bx = sx[j], by = sy[j];
    sx[i] = c * ax + s * by;  sy[i] = c * ay - s * bx;
    sx[j] = c * bx + s * ay;  sy[j] = c * by - s * ax;
  }
}

template <int TB>
__device__ __forceinline__ void ap_ry(float (&sx)[16], float (&sy)[16],
                                      float c, float s) {
#pragma unroll
  for (int i = 0; i < 16; ++i) {
    if (i & TB) continue;
    const int j = i | TB;
    float ax = sx[i], ay = sy[i], bx = sx[j], by = sy[j];
    sx[i] = c * ax - s * bx;  sy[i] = c * ay - s * by;
    sx[j] = s * ax + c * bx;  sy[j] = s * ay + c * by;
  }
}

template <int TB>
__device__ __forceinline__ void ap_rz(float (&sx)[16], float (&sy)[16],
                                      float c, float s) {
#pragma unroll
  for (int i = 0; i < 16; ++i) {
    if (i & TB) continue;
    const int j = i | TB;
    float ax = sx[i], ay = sy[i], bx = sx[j], by = sy[j];
    sx[i] = c * ax + s * ay;  sy[i] = c * ay - s * ax;
    sx[j] = c * bx - s * by;  sy[j] = c * by + s * bx;
  }
}

template <int TB>
__device__ __forceinline__ void ap_h(float (&sx)[16], float (&sy)[16]) {
  const float r = 0.70710678118654752f;
#pragma unroll
  for (int i = 0; i < 16; ++i) {
    if (i & TB) continue;
    const int j = i | TB;
    float ax = sx[i], ay = sy[i], bx = sx[j], by = sy[j];
    sx[i] = r * (ax + bx);  sy[i] = r * (ay + by);
    sx[j] = r * (ax - bx);  sy[j] = r * (ay - by);
  }
}

template <int TB>
__device__ __forceinline__ void ap_sxg(float (&sx)[16], float (&sy)[16]) {
#pragma unroll
  for (int i = 0; i < 16; ++i) {
    if (i & TB) continue;
    const int j = i | TB;
    float ax = sx[i], ay = sy[i], bx = sx[j], by = sy[j];
    sx[i] = 0.5f * (ax - ay + bx + by);  sy[i] = 0.5f * (ay + ax + by - bx);
    sx[j] = 0.5f * (ax + ay + bx - by);  sy[j] = 0.5f * (ay - ax + by + bx);
  }
}

template <int CB, int TB>
__device__ __forceinline__ void ap_cnot(float (&sx)[16], float (&sy)[16]) {
#pragma unroll
  for (int i = 0; i < 16; ++i) {
    if (!(i & CB) || (i & TB)) continue;
    const int j = i | TB;
    float tx = sx[i], ty = sy[i];
    sx[i] = sx[j]; sy[i] = sy[j];
    sx[j] = tx;    sy[j] = ty;
  }
}

template <int CB, int TB>
__device__ __forceinline__ void ap_crx(float (&sx)[16], float (&sy)[16],
                                       float c, float s) {
#pragma unroll
  for (int i = 0; i < 16; ++i) {
    if (!(i & CB) || (i & TB)) continue;
    const int j = i | TB;
    float ax = sx[i], ay = sy[i], bx = sx[j], by = sy[j];
    sx[i] = c * ax + s * by;  sy[i] = c * ay - s * bx;
    sx[j] = c * bx + s * ay;  sy[j] = c * by - s * ax;
  }
}

// ============== compile-time-unrolled gate chain over [G, GEND) =============
template <int G, int GEND>
__device__ __forceinline__ void apply_range(
    float (&sx)[16], float (&sy)[16], const float* __restrict__ rp,
    const float* __restrict__ rx0, const float* __restrict__ ry0,
    const float* __restrict__ rz0, const float* __restrict__ crx0) {
  if constexpr (G < GEND) {
    constexpr int kind = GL.kind[G];
    constexpr int TB0 = 8 >> GL.w0[G];
    constexpr int TB1 = 8 >> GL.w1[G];
    constexpr int pi = GL.pidx[G];
    float c = 0.f, s = 0.f;
    if constexpr (kind == 0 || kind == 1 || kind == 2 || kind == 4) {
      float th;
      if constexpr (pi >= 0)       th = rp[pi];
      else if constexpr (pi == -2) th = rx0[0];
      else if constexpr (pi == -3) th = ry0[0];
      else if constexpr (pi == -4) th = rz0[0];
      else                         th = crx0[0];
      float h = 0.5f * th;
      s = __sinf(h);
      c = __cosf(h);
    }
    if constexpr (kind == 0)      ap_rx<TB0>(sx, sy, c, s);
    else if constexpr (kind == 1) ap_ry<TB0>(sx, sy, c, s);
    else if constexpr (kind == 2) ap_rz<TB0>(sx, sy, c, s);
    else if constexpr (kind == 3) ap_cnot<TB0, TB1>(sx, sy);
    else if constexpr (kind == 4) ap_crx<TB0, TB1>(sx, sy, c, s);
    else if constexpr (kind == 5) ap_h<TB0>(sx, sy);
    else                          ap_sxg<TB0>(sx, sy);
    apply_range<G + 1, GEND>(sx, sy, rp, rx0, ry0, rz0, crx0);
  }
}

// ===================== per-element helpers ==================================
__device__ __forceinline__ void phase1(const float* __restrict__ features,
                                       long long b, float (&t01x)[4],
                                       float (&t01y)[4], float (&t23x)[4],
                                       float (&t23y)[4]) {
  const float4* fp = (const float4*)(features + b * 16);
  float4 F0 = fp[0], F1 = fp[1], F2 = fp[2], F3 = fp[3];
  float L0[4] = {F0.x, F0.y, F0.z, F0.w};
  float L1[4] = {F1.x, F1.y, F1.z, F1.w};
  float L2[4] = {F2.x, F2.y, F2.z, F2.w};
  float L3[4] = {F3.x, F3.y, F3.z, F3.w};
  float vax[4], vay[4], vbx[4], vby[4];
#pragma unroll
  for (int w = 0; w < 4; ++w) {
    float h0 = 0.5f * L0[w], h1 = 0.5f * L1[w];
    float h2 = 0.5f * L2[w], h3 = 0.5f * L3[w];
    float s0 = __sinf(h0), c0 = __cosf(h0);
    float s1 = __sinf(h1), c1 = __cosf(h1);
    float s2 = __sinf(h2), c2 = __cosf(h2);
    float s3 = __sinf(h3), c3 = __cosf(h3);
    float ax = c0 * c1, ay = -c0 * s1;
    float bx = s0 * c1, by = s0 * s1;
    float a2x = c2 * ax + s2 * by, a2y = c2 * ay - s2 * bx;
    float b2x = s2 * ay + c2 * bx, b2y = -s2 * ax + c2 * by;
    vax[w] = c3 * a2x - s3 * b2x; vay[w] = c3 * a2y - s3 * b2y;
    vbx[w] = s3 * a2x + c3 * b2x; vby[w] = s3 * a2y + c3 * b2y;
  }
  t01x[0] = vax[0] * vax[1] - vay[0] * vay[1]; t01y[0] = vax[0] * vay[1] + vay[0] * vax[1];
  t01x[1] = vax[0] * vbx[1] - vay[0] * vby[1]; t01y[1] = vax[0] * vby[1] + vay[0] * vbx[1];
  t01x[2] = vbx[0] * vax[1] - vby[0] * vay[1]; t01y[2] = vbx[0] * vay[1] + vby[0] * vax[1];
  t01x[3] = vbx[0] * vbx[1] - vby[0] * vby[1]; t01y[3] = vbx[0] * vby[1] + vby[0] * vbx[1];
  t23x[0] = vax[2] * vax[3] - vay[2] * vay[3]; t23y[0] = vax[2] * vay[3] + vay[2] * vax[3];
  t23x[1] = vax[2] * vbx[3] - vay[2] * vby[3]; t23y[1] = vax[2] * vby[3] + vay[2] * vbx[3];
  t23x[2] = vbx[2] * vax[3] - vby[2] * vay[3]; t23y[2] = vbx[2] * vay[3] + vby[2] * vax[3];
  t23x[3] = vbx[2] * vbx[3] - vby[2] * vby[3]; t23y[3] = vbx[2] * vby[3] + vby[2] * vbx[3];
}

// phase 2: PK-packed complex matvec; all U indices compile-time-uniform.
__device__ __forceinline__ void phase2_pk(const float4* __restrict__ U4,
                                          const float (&t01x)[4], const float (&t01y)[4],
                                          const float (&t23x)[4], const float (&t23y)[4],
                                          float (&ez)[4]) {
  float2 sv[16], nv[16];
#pragma unroll
  for (int i = 0; i < 16; ++i) {
    int a = i >> 2, c = i & 3;
    float sxv = t01x[a] * t23x[c] - t01y[a] * t23y[c];
    float syv = t01x[a] * t23y[c] + t01y[a] * t23x[c];
    sv[i] = make_float2(sxv, syv);
    nv[i] = make_float2(-syv, sxv);
  }
  float e0 = 0.f, e1 = 0.f, e2 = 0.f, e3 = 0.f;
#pragma unroll
  for (int i = 0; i < 16; ++i) {
    float2 a0 = make_float2(0.f, 0.f), a1 = make_float2(0.f, 0.f);
#pragma unroll
    for (int j2 = 0; j2 < 8; j2 += 2) {
      float4 u0 = U4[i * 8 + j2];       // (re0, im0, re1, im1), uniform
      float4 u1 = U4[i * 8 + j2 + 1];
      int j = 2 * j2;
      a0 = a0 + sv[j] * u0.x + nv[j] * u0.y + sv[j + 1] * u0.z + nv[j + 1] * u0.w;
      a1 = a1 + sv[j + 2] * u1.x + nv[j + 2] * u1.y + sv[j + 3] * u1.z +
           nv[j + 3] * u1.w;
    }
    float2 a = a0 + a1;
    float p = a.x * a.x + a.y * a.y;
    e0 += (i & 8) ? -p : p;
    e1 += (i & 4) ? -p : p;
    e2 += (i & 2) ? -p : p;
    e3 += (i & 1) ? -p : p;
  }
  ez[0] = e0; ez[1] = e1; ez[2] = e2; ez[3] = e3;
}

// =================== K_A: build U once (1 block, 4 waves) ===================
__global__ __launch_bounds__(256) void build_u_kernel(
    const float* __restrict__ rand_params, const float* __restrict__ rx0,
    const float* __restrict__ ry0, const float* __restrict__ rz0,
    const float* __restrict__ crx0, float2* __restrict__ U_out) {
  __shared__ float2 chunks[4][256];
  __shared__ float2 comb[2][256];
  int tid = threadIdx.x;
  int wv = tid >> 6, lane = tid & 63;

  if (lane < 16) {
    float sx[16], sy[16];
#pragma unroll
    for (int i = 0; i < 16; ++i) { sx[i] = (i == lane) ? 1.f : 0.f; sy[i] = 0.f; }
    if (wv == 0)      apply_range<0,   CK1  >(sx, sy, rand_params, rx0, ry0, rz0, crx0);
    else if (wv == 1) apply_range<CK1, CK2  >(sx, sy, rand_params, rx0, ry0, rz0, crx0);
    else if (wv == 2) apply_range<CK2, CK3  >(sx, sy, rand_params, rx0, ry0, rz0, crx0);
    else              apply_range<CK3, GL.ng>(sx, sy, rand_params, rx0, ry0, rz0, crx0);
#pragma unroll
    for (int i = 0; i < 16; ++i)
      chunks[wv][i * 16 + lane] = make_float2(sx[i], sy[i]);
  }
  __syncthreads();

  {
    int r = tid >> 4, c = tid & 15;
    float xr = 0.f, xi = 0.f, yr = 0.f, yi = 0.f;
#pragma unroll
    for (int k = 0; k < 16; ++k) {
      float2 g1 = chunks[1][r * 16 + k], g0 = chunks[0][k * 16 + c];
      xr += g1.x * g0.x - g1.y * g0.y;  xi += g1.x * g0.y + g1.y * g0.x;
      float2 g3 = chunks[3][r * 16 + k], g2 = chunks[2][k * 16 + c];
      yr += g3.x * g2.x - g3.y * g2.y;  yi += g3.x * g2.y + g3.y * g2.x;
    }
    comb[0][r * 16 + c] = make_float2(xr, xi);
    comb[1][r * 16 + c] = make_float2(yr, yi);
  }
  __syncthreads();

  {
    int r = tid >> 4, c = tid & 15;
    float ur = 0.f, ui = 0.f;
#pragma unroll
    for (int k = 0; k < 16; ++k) {
      float2 a = comb[1][r * 16 + k], d = comb[0][k * 16 + c];
      ur += a.x * d.x - a.y * d.y;
      ui += a.x * d.y + a.y * d.x;
    }
    U_out[r * 16 + c] = make_float2(ur, ui);
  }
}

// ============== K_B: encoder + pk matvec + ez + block partials ==============
__global__ __launch_bounds__(256) void main_kernel(
    const float* __restrict__ features, const float4* __restrict__ U4,
    float* __restrict__ ez_out, float* __restrict__ partials, int B, int useEz) {
  __shared__ float wred[4][8];
  int tid = threadIdx.x;

  long long b = (long long)blockIdx.x * 256 + tid;
  bool valid = b < B;
  float ez[4] = {0.f, 0.f, 0.f, 0.f};
  if (valid) {
    float t01x[4], t01y[4], t23x[4], t23y[4];
    phase1(features, b, t01x, t01y, t23x, t23y);
    phase2_pk(U4, t01x, t01y, t23x, t23y, ez);
    if (useEz) ((float4*)ez_out)[b] = make_float4(ez[0], ez[1], ez[2], ez[3]);
  }
  float q[8] = {ez[0], ez[1], ez[2], ez[3],
                ez[0] * ez[0], ez[1] * ez[1], ez[2] * ez[2], ez[3] * ez[3]};
#pragma unroll
  for (int off = 32; off; off >>= 1)
#pragma unroll
    for (int k = 0; k < 8; ++k) q[k] += __shfl_down(q[k], off, 64);
  int lane = tid & 63, wv = tid >> 6;
  if (lane == 0)
#pragma unroll
    for (int k = 0; k < 8; ++k) wred[wv][k] = q[k];
  __syncthreads();
  if (tid == 0) {
#pragma unroll
    for (int k = 0; k < 8; ++k)
      partials[(size_t)blockIdx.x * 8 + k] =
          wred[0][k] + wred[1][k] + wred[2][k] + wred[3][k];
  }
}

// ========= K_C: redundant stats reduce -> coefs -> output pass ==============
__global__ __launch_bounds__(256) void out_kernel(
    const float* __restrict__ partials, int nblk,
    const float* __restrict__ gamma, const float* __restrict__ beta,
    const float* __restrict__ W, const float* __restrict__ bias,
    const float* __restrict__ ez_in, const float* __restrict__ features,
    const float4* __restrict__ U4, float* __restrict__ out,
    int B, int useEz, float invB) {
  __shared__ float wred[4][8];
  __shared__ float coefs[5];
  int tid = threadIdx.x;

  float q[8] = {0.f, 0.f, 0.f, 0.f, 0.f, 0.f, 0.f, 0.f};
  for (int idx = tid; idx < nblk; idx += 256) {
    const float4* p4 = (const float4*)(partials + (size_t)idx * 8);
    float4 A = p4[0], Bq = p4[1];
    q[0] += A.x;  q[1] += A.y;  q[2] += A.z;  q[3] += A.w;
    q[4] += Bq.x; q[5] += Bq.y; q[6] += Bq.z; q[7] += Bq.w;
  }
#pragma unroll
  for (int off = 32; off; off >>= 1)
#pragma unroll
    for (int k = 0; k < 8; ++k) q[k] += __shfl_down(q[k], off, 64);
  int lane = tid & 63, wv = tid >> 6;
  if (lane == 0)
#pragma unroll
    for (int k = 0; k < 8; ++k) wred[wv][k] = q[k];
  __syncthreads();
  if (tid == 0) {
    float c0 = bias[0];
#pragma unroll
    for (int w = 0; w < 4; ++w) {
      float Sw = wred[0][w] + wred[1][w] + wred[2][w] + wred[3][w];
      float Qw = wred[0][4 + w] + wred[1][4 + w] + wred[2][4 + w] + wred[3][4 + w];
      float mu = Sw * invB;
      float var = Qw * invB - mu * mu;
      float inv = rsqrtf(var + 1e-5f);
      coefs[w] = W[w] * gamma[w] * inv;
      c0 += W[w] * (beta[w] - gamma[w] * mu * inv);
    }
    coefs[4] = c0;
  }
  __syncthreads();

  long long b = (long long)blockIdx.x * 256 + tid;
  if (b >= B) return;
  float ez[4] = {0.f, 0.f, 0.f, 0.f};
  if (useEz) {
    float4 e = ((const float4*)ez_in)[b];
    ez[0] = e.x; ez[1] = e.y; ez[2] = e.z; ez[3] = e.w;
  } else {
    float t01x[4], t01y[4], t23x[4], t23y[4];
    phase1(features, b, t01x, t01y, t23x, t23y);
    phase2_pk(U4, t01x, t01y, t23x, t23y, ez);
  }
  out[b] = coefs[4] + coefs[0] * ez[0] + coefs[1] * ez[1] +
           coefs[2] * ez[2] + coefs[3] * ez[3];
}

// ================================ launch ====================================
extern "C" void kernel_launch(void* const* d_in, const int* in_sizes, int n_in,
                              void* d_out, int out_size, void* d_ws, size_t ws_size,
                              hipStream_t stream) {
  const float* features    = (const float*)d_in[0];
  const float* rand_params = (const float*)d_in[1];
  const float* rx0         = (const float*)d_in[2];
  const float* ry0         = (const float*)d_in[3];
  const float* rz0         = (const float*)d_in[4];
  const float* crx0        = (const float*)d_in[5];
  const float* gamma       = (const float*)d_in[6];
  const float* beta        = (const float*)d_in[7];
  const float* W           = (const float*)d_in[8];
  const float* bias        = (const float*)d_in[9];
  float* out = (float*)d_out;

  int B = in_sizes[0] / 16;
  int nblk = (B + 255) / 256;

  char* ws = (char*)d_ws;
  float2* U = (float2*)ws;                                    // 2048 B
  float* partials = (float*)(ws + 2048);                      // nblk*32 B
  size_t ez_off = (2048 + (size_t)nblk * 32 + 255) & ~(size_t)255;
  float* ez = (float*)(ws + ez_off);
  int useEz = (ws_size >= ez_off + (size_t)B * 16) ? 1 : 0;

  build_u_kernel<<<1, 256, 0, stream>>>(rand_params, rx0, ry0, rz0, crx0, U);
  // MEASUREMENT: K_B launched twice (idempotent). dur - 22.6us = K_B cost.
  main_kernel<<<nblk, 256, 0, stream>>>(features, (const float4*)U, ez,
                                        partials, B, useEz);
  main_kernel<<<nblk, 256, 0, stream>>>(features, (const float4*)U, ez,
                                        partials, B, useEz);
  out_kernel<<<nblk, 256, 0, stream>>>(partials, nblk, gamma, beta, W, bias,
                                       ez, features, (const float4*)U, out,
                                       B, useEz, 1.0f / (float)B);
}

// Round 15
// 21.090 us; speedup vs baseline: 1.3767x; 1.3767x over previous
//
#include <hip/hip_runtime.h>
#include <math.h>

// ---------------------------------------------------------------------------
// FraudDetectionHybrid: 4-qubit statevector sim, algebraically collapsed.
// TWO kernels:
//   K_B (513 blk): block 0 = BUILDER (constexpr-MT19937(42) gate chunks by 4
//       waves + 2 LDS combine matmuls -> U to ws via relaxed agent atomics +
//       vmcnt + 64 release-flag copies). Blocks 1..512: phase1 (hides build),
//       poll flag, copy U->LDS (relaxed atomic loads; plain loads may see
//       stale per-XCD L2 - G16), pk matvec, ez + block partials.
//       Replay-safe: stale MAGIC flag benign (U rewritten bit-identical).
//       Deadlock-safe: (256,4) -> >=4 blk/CU -> 1024 capacity >= 513.
//   K_C (512 blk): redundant partial reduce -> BN+Linear coefs -> out.
//
// R14 MEASUREMENT: K_B(warm) = 6.5us (29.03-22.57). So fixed~4.8 + K_B 6.5
// leaves ~11us in K_A + K_C + gaps -> K_A's serial 1-block dispatch is the
// target: deleted here, build hidden under phase1.
// History: R1-R3 scratch fixes; R4 dispatch ~0.5us; R5-R8 grid barriers lose
// to dispatch boundaries (R8 pattern reused here for one-way publish);
// R9/R10 native trig + s_load U; R11/R13 TLP splits null; R12 pk matvec -1.6.
// ---------------------------------------------------------------------------

#define MAGIC 0x5CA1AB1Eu
#define RLX __ATOMIC_RELAXED
#define ACQ __ATOMIC_ACQUIRE
#define REL __ATOMIC_RELEASE
#define AGT __HIP_MEMORY_SCOPE_AGENT

// ==================== compile-time numpy RandomState(42) ====================
struct CGates {
  int kind[64];   // 0=RX 1=RY 2=RZ 3=CNOT 4=CRX 5=H 6=SX
  int w0[64];
  int w1[64];
  int pidx[64];   // >=0: rand_params idx; -1 none; -2 rx0; -3 ry0; -4 rz0; -5 crx0
  int ng;
};

constexpr unsigned int c_mt_next(unsigned int (&mt)[624], int& pos) {
  if (pos >= 624) {
    for (int i = 0; i < 624; ++i) {
      unsigned int y = (mt[i] & 0x80000000u) | (mt[(i + 1) % 624] & 0x7fffffffu);
      unsigned int v = mt[(i + 397) % 624] ^ (y >> 1);
      if (y & 1u) v ^= 0x9908b0dfu;
      mt[i] = v;
    }
    pos = 0;
  }
  unsigned int y = mt[pos++];
  y ^= y >> 11;
  y ^= (y << 7) & 0x9d2c5680u;
  y ^= (y << 15) & 0xefc60000u;
  y ^= y >> 18;
  return y;
}

constexpr CGates make_gates() {
  CGates gl{};
  unsigned int mt[624] = {};
  mt[0] = 42u;
  for (int i = 1; i < 624; ++i)
    mt[i] = 1812433253u * (mt[i - 1] ^ (mt[i - 1] >> 30)) + (unsigned int)i;
  int pos = 624;
  int ng = 0, p = 0;
  for (int op = 0; op < 50; ++op) {
    unsigned int k = c_mt_next(mt, pos) & 3u;   // randint(4): one draw, mask 3
    if (k < 3u) {
      unsigned int w = c_mt_next(mt, pos) & 3u; // wire
      gl.kind[ng] = (int)k; gl.w0[ng] = (int)w; gl.w1[ng] = 0;
      gl.pidx[ng] = p++;
      ++ng;
    } else {
      // choice(4,2,replace=False): Fisher-Yates descending, mask-rejection
      int arr[4] = {0, 1, 2, 3};
      { unsigned int j = c_mt_next(mt, pos) & 3u;
        int t = arr[3]; arr[3] = arr[j]; arr[j] = t; }
      { unsigned int j = c_mt_next(mt, pos) & 3u;
        while (j > 2u) j = c_mt_next(mt, pos) & 3u;
        int t = arr[2]; arr[2] = arr[j]; arr[j] = t; }
      { unsigned int j = c_mt_next(mt, pos) & 1u;
        int t = arr[1]; arr[1] = arr[j]; arr[j] = t; }
      gl.kind[ng] = 3; gl.w0[ng] = arr[0]; gl.w1[ng] = arr[1]; gl.pidx[ng] = -1;
      ++ng;
    }
  }
  // trainable block
  gl.kind[ng] = 0; gl.w0[ng] = 0; gl.w1[ng] = 0; gl.pidx[ng] = -2; ++ng; // RX w0
  gl.kind[ng] = 1; gl.w0[ng] = 1; gl.w1[ng] = 0; gl.pidx[ng] = -3; ++ng; // RY w1
  gl.kind[ng] = 2; gl.w0[ng] = 3; gl.w1[ng] = 0; gl.pidx[ng] = -4; ++ng; // RZ w3
  gl.kind[ng] = 4; gl.w0[ng] = 0; gl.w1[ng] = 2; gl.pidx[ng] = -5; ++ng; // CRX(0,2)
  gl.kind[ng] = 5; gl.w0[ng] = 3; gl.w1[ng] = 0; gl.pidx[ng] = -1; ++ng; // H w3
  gl.kind[ng] = 6; gl.w0[ng] = 2; gl.w1[ng] = 0; gl.pidx[ng] = -1; ++ng; // SX w2
  gl.kind[ng] = 3; gl.w0[ng] = 3; gl.w1[ng] = 0; gl.pidx[ng] = -1; ++ng; // CNOT(3,0)
  gl.ng = ng;
  return gl;
}

inline constexpr CGates GL = make_gates();

inline constexpr int CK1 = GL.ng / 4;
inline constexpr int CK2 = GL.ng / 2;
inline constexpr int CK3 = (3 * GL.ng) / 4;

// ================= templated gate appliers (static indices) =================
// wire0 = MSB (bit 3): TB = 8 >> wire.

template <int TB>
__device__ __forceinline__ void ap_rx(float (&sx)[16], float (&sy)[16],
                                      float c, float s) {
#pragma unroll
  for (int i = 0; i < 16; ++i) {
    if (i & TB) continue;
    const int j = i | TB;
    float ax = sx[i], ay = sy[i], bx = sx[j], by = sy[j];
    sx[i] = c * ax + s * by;  sy[i] = c * ay - s * bx;
    sx[j] = c * bx + s * ay;  sy[j] = c * by - s * ax;
  }
}

template <int TB>
__device__ __forceinline__ void ap_ry(float (&sx)[16], float (&sy)[16],
                                      float c, float s) {
#pragma unroll
  for (int i = 0; i < 16; ++i) {
    if (i & TB) continue;
    const int j = i | TB;
    float ax = sx[i], ay = sy[i], bx = sx[j], by = sy[j];
    sx[i] = c * ax - s * bx;  sy[i] = c * ay - s * by;
    sx[j] = s * ax + c * bx;  sy[j] = s * ay + c * by;
  }
}

template <int TB>
__device__ __forceinline__ void ap_rz(float (&sx)[16], float (&sy)[16],
                                      float c, float s) {
#pragma unroll
  for (int i = 0; i < 16; ++i) {
    if (i & TB) continue;
    const int j = i | TB;
    float ax = sx[i], ay = sy[i], bx = sx[j], by = sy[j];
    sx[i] = c * ax + s * ay;  sy[i] = c * ay - s * ax;
    sx[j] = c * bx - s * by;  sy[j] = c * by + s * bx;
  }
}

template <int TB>
__device__ __forceinline__ void ap_h(float (&sx)[16], float (&sy)[16]) {
  const float r = 0.70710678118654752f;
#pragma unroll
  for (int i = 0; i < 16; ++i) {
    if (i & TB) continue;
    const int j = i | TB;
    float ax = sx[i], ay = sy[i], bx = sx[j], by = sy[j];
    sx[i] = r * (ax + bx);  sy[i] = r * (ay + by);
    sx[j] = r * (ax - bx);  sy[j] = r * (ay - by);
  }
}

template <int TB>
__device__ __forceinline__ void ap_sxg(float (&sx)[16], float (&sy)[16]) {
#pragma unroll
  for (int i = 0; i < 16; ++i) {
    if (i & TB) continue;
    const int j = i | TB;
    float ax = sx[i], ay = sy[i], bx = sx[j], by = sy[j];
    sx[i] = 0.5f * (ax - ay + bx + by);  sy[i] = 0.5f * (ay + ax + by - bx);
    sx[j] = 0.5f * (ax + ay + bx - by);  sy[j] = 0.5f * (ay - ax + by + bx);
  }
}

template <int CB, int TB>
__device__ __forceinline__ void ap_cnot(float (&sx)[16], float (&sy)[16]) {
#pragma unroll
  for (int i = 0; i < 16; ++i) {
    if (!(i & CB) || (i & TB)) continue;
    const int j = i | TB;
    float tx = sx[i], ty = sy[i];
    sx[i] = sx[j]; sy[i] = sy[j];
    sx[j] = tx;    sy[j] = ty;
  }
}

template <int CB, int TB>
__device__ __forceinline__ void ap_crx(float (&sx)[16], float (&sy)[16],
                                       float c, float s) {
#pragma unroll
  for (int i = 0; i < 16; ++i) {
    if (!(i & CB) || (i & TB)) continue;
    const int j = i | TB;
    float ax = sx[i], ay = sy[i], bx = sx[j], by = sy[j];
    sx[i] = c * ax + s * by;  sy[i] = c * ay - s * bx;
    sx[j] = c * bx + s * ay;  sy[j] = c * by - s * ax;
  }
}

// ============== compile-time-unrolled gate chain over [G, GEND) =============
template <int G, int GEND>
__device__ __forceinline__ void apply_range(
    float (&sx)[16], float (&sy)[16], const float* __restrict__ rp,
    const float* __restrict__ rx0, const float* __restrict__ ry0,
    const float* __restrict__ rz0, const float* __restrict__ crx0) {
  if constexpr (G < GEND) {
    constexpr int kind = GL.kind[G];
    constexpr int TB0 = 8 >> GL.w0[G];
    constexpr int TB1 = 8 >> GL.w1[G];
    constexpr int pi = GL.pidx[G];
    float c = 0.f, s = 0.f;
    if constexpr (kind == 0 || kind == 1 || kind == 2 || kind == 4) {
      float th;
      if constexpr (pi >= 0)       th = rp[pi];
      else if constexpr (pi == -2) th = rx0[0];
      else if constexpr (pi == -3) th = ry0[0];
      else if constexpr (pi == -4) th = rz0[0];
      else                         th = crx0[0];
      float h = 0.5f * th;
      s = __sinf(h);
      c = __cosf(h);
    }
    if constexpr (kind == 0)      ap_rx<TB0>(sx, sy, c, s);
    else if constexpr (kind == 1) ap_ry<TB0>(sx, sy, c, s);
    else if constexpr (kind == 2) ap_rz<TB0>(sx, sy, c, s);
    else if constexpr (kind == 3) ap_cnot<TB0, TB1>(sx, sy);
    else if constexpr (kind == 4) ap_crx<TB0, TB1>(sx, sy, c, s);
    else if constexpr (kind == 5) ap_h<TB0>(sx, sy);
    else                          ap_sxg<TB0>(sx, sy);
    apply_range<G + 1, GEND>(sx, sy, rp, rx0, ry0, rz0, crx0);
  }
}

// ===================== per-element helpers ==================================
__device__ __forceinline__ void phase1(const float* __restrict__ features,
                                       long long b, float (&t01x)[4],
                                       float (&t01y)[4], float (&t23x)[4],
                                       float (&t23y)[4]) {
  const float4* fp = (const float4*)(features + b * 16);
  float4 F0 = fp[0], F1 = fp[1], F2 = fp[2], F3 = fp[3];
  float L0[4] = {F0.x, F0.y, F0.z, F0.w};
  float L1[4] = {F1.x, F1.y, F1.z, F1.w};
  float L2[4] = {F2.x, F2.y, F2.z, F2.w};
  float L3[4] = {F3.x, F3.y, F3.z, F3.w};
  float vax[4], vay[4], vbx[4], vby[4];
#pragma unroll
  for (int w = 0; w < 4; ++w) {
    float h0 = 0.5f * L0[w], h1 = 0.5f * L1[w];
    float h2 = 0.5f * L2[w], h3 = 0.5f * L3[w];
    float s0 = __sinf(h0), c0 = __cosf(h0);
    float s1 = __sinf(h1), c1 = __cosf(h1);
    float s2 = __sinf(h2), c2 = __cosf(h2);
    float s3 = __sinf(h3), c3 = __cosf(h3);
    float ax = c0 * c1, ay = -c0 * s1;
    float bx = s0 * c1, by = s0 * s1;
    float a2x = c2 * ax + s2 * by, a2y = c2 * ay - s2 * bx;
    float b2x = s2 * ay + c2 * bx, b2y = -s2 * ax + c2 * by;
    vax[w] = c3 * a2x - s3 * b2x; vay[w] = c3 * a2y - s3 * b2y;
    vbx[w] = s3 * a2x + c3 * b2x; vby[w] = s3 * a2y + c3 * b2y;
  }
  t01x[0] = vax[0] * vax[1] - vay[0] * vay[1]; t01y[0] = vax[0] * vay[1] + vay[0] * vax[1];
  t01x[1] = vax[0] * vbx[1] - vay[0] * vby[1]; t01y[1] = vax[0] * vby[1] + vay[0] * vbx[1];
  t01x[2] = vbx[0] * vax[1] - vby[0] * vay[1]; t01y[2] = vbx[0] * vay[1] + vby[0] * vax[1];
  t01x[3] = vbx[0] * vbx[1] - vby[0] * vby[1]; t01y[3] = vbx[0] * vby[1] + vby[0] * vbx[1];
  t23x[0] = vax[2] * vax[3] - vay[2] * vay[3]; t23y[0] = vax[2] * vay[3] + vay[2] * vax[3];
  t23x[1] = vax[2] * vbx[3] - vay[2] * vby[3]; t23y[1] = vax[2] * vby[3] + vay[2] * vbx[3];
  t23x[2] = vbx[2] * vax[3] - vby[2] * vay[3]; t23y[2] = vbx[2] * vay[3] + vby[2] * vax[3];
  t23x[3] = vbx[2] * vbx[3] - vby[2] * vby[3]; t23y[3] = vbx[2] * vby[3] + vby[2] * vbx[3];
}

// phase 2: PK-packed complex matvec; compile-time row indices.
__device__ __forceinline__ void phase2_pk(const float4* U4,
                                          const float (&t01x)[4], const float (&t01y)[4],
                                          const float (&t23x)[4], const float (&t23y)[4],
                                          float (&ez)[4]) {
  float2 sv[16], nv[16];
#pragma unroll
  for (int i = 0; i < 16; ++i) {
    int a = i >> 2, c = i & 3;
    float sxv = t01x[a] * t23x[c] - t01y[a] * t23y[c];
    float syv = t01x[a] * t23y[c] + t01y[a] * t23x[c];
    sv[i] = make_float2(sxv, syv);
    nv[i] = make_float2(-syv, sxv);
  }
  float e0 = 0.f, e1 = 0.f, e2 = 0.f, e3 = 0.f;
#pragma unroll
  for (int i = 0; i < 16; ++i) {
    float2 a0 = make_float2(0.f, 0.f), a1 = make_float2(0.f, 0.f);
#pragma unroll
    for (int j2 = 0; j2 < 8; j2 += 2) {
      float4 u0 = U4[i * 8 + j2];       // (re0, im0, re1, im1)
      float4 u1 = U4[i * 8 + j2 + 1];
      int j = 2 * j2;
      a0 = a0 + sv[j] * u0.x + nv[j] * u0.y + sv[j + 1] * u0.z + nv[j + 1] * u0.w;
      a1 = a1 + sv[j + 2] * u1.x + nv[j + 2] * u1.y + sv[j + 3] * u1.z +
           nv[j + 3] * u1.w;
    }
    float2 a = a0 + a1;
    float p = a.x * a.x + a.y * a.y;
    e0 += (i & 8) ? -p : p;
    e1 += (i & 4) ? -p : p;
    e2 += (i & 2) ? -p : p;
    e3 += (i & 1) ? -p : p;
  }
  ez[0] = e0; ez[1] = e1; ez[2] = e2; ez[3] = e3;
}

// ==== K_B: block 0 = builder; blocks 1..nblk = elements (flag handshake) ====
__global__ __launch_bounds__(256, 4) void main_kernel(
    const float* __restrict__ features, const float* __restrict__ rand_params,
    const float* __restrict__ rx0, const float* __restrict__ ry0,
    const float* __restrict__ rz0, const float* __restrict__ crx0,
    float* __restrict__ Uws, float* __restrict__ ez_out,
    float* __restrict__ partials, int B, int useEz) {
  __shared__ float2 chunks[4][256];   // block0: build; others: [0] = U copy
  __shared__ float2 comb[2][256];
  __shared__ float wred[4][8];
  int tid = threadIdx.x;
  int bid = blockIdx.x;
  int wv = tid >> 6, lane = tid & 63;
  unsigned int* flagbase = (unsigned int*)(Uws + 512);  // 64 flags, 128B apart

  if (bid == 0) {
    // ---- builder: 4-wave chunk build + 2 combine rounds ----
    if (lane < 16) {
      float sx[16], sy[16];
#pragma unroll
      for (int i = 0; i < 16; ++i) { sx[i] = (i == lane) ? 1.f : 0.f; sy[i] = 0.f; }
      if (wv == 0)      apply_range<0,   CK1  >(sx, sy, rand_params, rx0, ry0, rz0, crx0);
      else if (wv == 1) apply_range<CK1, CK2  >(sx, sy, rand_params, rx0, ry0, rz0, crx0);
      else if (wv == 2) apply_range<CK2, CK3  >(sx, sy, rand_params, rx0, ry0, rz0, crx0);
      else              apply_range<CK3, GL.ng>(sx, sy, rand_params, rx0, ry0, rz0, crx0);
#pragma unroll
      for (int i = 0; i < 16; ++i)
        chunks[wv][i * 16 + lane] = make_float2(sx[i], sy[i]);
    }
    __syncthreads();
    {
      int r = tid >> 4, c = tid & 15;
      float xr = 0.f, xi = 0.f, yr = 0.f, yi = 0.f;
#pragma unroll
      for (int k = 0; k < 16; ++k) {
        float2 g1 = chunks[1][r * 16 + k], g0 = chunks[0][k * 16 + c];
        xr += g1.x * g0.x - g1.y * g0.y;  xi += g1.x * g0.y + g1.y * g0.x;
        float2 g3 = chunks[3][r * 16 + k], g2 = chunks[2][k * 16 + c];
        yr += g3.x * g2.x - g3.y * g2.y;  yi += g3.x * g2.y + g3.y * g2.x;
      }
      comb[0][r * 16 + c] = make_float2(xr, xi);
      comb[1][r * 16 + c] = make_float2(yr, yi);
    }
    __syncthreads();
    {
      int r = tid >> 4, c = tid & 15;
      float ur = 0.f, ui = 0.f;
#pragma unroll
      for (int k = 0; k < 16; ++k) {
        float2 a = comb[1][r * 16 + k], d = comb[0][k * 16 + c];
        ur += a.x * d.x - a.y * d.y;
        ui += a.x * d.y + a.y * d.x;
      }
      // publish U element (agent-scope, bypasses per-XCD L2)
      __hip_atomic_store(&Uws[2 * tid], ur, RLX, AGT);
      __hip_atomic_store(&Uws[2 * tid + 1], ui, RLX, AGT);
    }
    asm volatile("s_waitcnt vmcnt(0)" ::: "memory");  // my stores complete
    __syncthreads();                                   // all threads' complete
    if (tid < 64)
      __hip_atomic_store(&flagbase[tid * 32], MAGIC, REL, AGT);
    return;  // builder-only block
  }

  // ---- element blocks ----
  long long b = (long long)(bid - 1) * 256 + tid;
  bool valid = b < B;
  float t01x[4], t01y[4], t23x[4], t23y[4];
  if (valid) phase1(features, b, t01x, t01y, t23x, t23y);  // hides U build

  if (tid == 0) {
    unsigned int* myflag = &flagbase[(bid & 63) * 32];
    while (__hip_atomic_load(myflag, ACQ, AGT) != MAGIC)
      __builtin_amdgcn_s_sleep(2);
  }
  __syncthreads();
  // copy U to LDS (atomic loads: plain loads may hit stale per-XCD L2)
  {
    float* Ul = (float*)&chunks[0][0];
    Ul[tid]       = __hip_atomic_load(&Uws[tid], RLX, AGT);
    Ul[tid + 256] = __hip_atomic_load(&Uws[tid + 256], RLX, AGT);
  }
  __syncthreads();

  float ez[4] = {0.f, 0.f, 0.f, 0.f};
  if (valid) {
    phase2_pk((const float4*)&chunks[0][0], t01x, t01y, t23x, t23y, ez);
    if (useEz) ((float4*)ez_out)[b] = make_float4(ez[0], ez[1], ez[2], ez[3]);
  }
  float q[8] = {ez[0], ez[1], ez[2], ez[3],
                ez[0] * ez[0], ez[1] * ez[1], ez[2] * ez[2], ez[3] * ez[3]};
#pragma unroll
  for (int off = 32; off; off >>= 1)
#pragma unroll
    for (int k = 0; k < 8; ++k) q[k] += __shfl_down(q[k], off, 64);
  if (lane == 0)
#pragma unroll
    for (int k = 0; k < 8; ++k) wred[wv][k] = q[k];
  __syncthreads();
  if (tid == 0) {
#pragma unroll
    for (int k = 0; k < 8; ++k)
      partials[(size_t)(bid - 1) * 8 + k] =
          wred[0][k] + wred[1][k] + wred[2][k] + wred[3][k];
  }
}

// ========= K_C: redundant stats reduce -> coefs -> output pass ==============
__global__ __launch_bounds__(256) void out_kernel(
    const float* __restrict__ partials, int nblk,
    const float* __restrict__ gamma, const float* __restrict__ beta,
    const float* __restrict__ W, const float* __restrict__ bias,
    const float* __restrict__ ez_in, const float* __restrict__ features,
    const float4* __restrict__ U4, float* __restrict__ out,
    int B, int useEz, float invB) {
  __shared__ float wred[4][8];
  __shared__ float coefs[5];
  int tid = threadIdx.x;

  float q[8] = {0.f, 0.f, 0.f, 0.f, 0.f, 0.f, 0.f, 0.f};
  for (int idx = tid; idx < nblk; idx += 256) {
    const float4* p4 = (const float4*)(partials + (size_t)idx * 8);
    float4 A = p4[0], Bq = p4[1];
    q[0] += A.x;  q[1] += A.y;  q[2] += A.z;  q[3] += A.w;
    q[4] += Bq.x; q[5] += Bq.y; q[6] += Bq.z; q[7] += Bq.w;
  }
#pragma unroll
  for (int off = 32; off; off >>= 1)
#pragma unroll
    for (int k = 0; k < 8; ++k) q[k] += __shfl_down(q[k], off, 64);
  int lane = tid & 63, wv = tid >> 6;
  if (lane == 0)
#pragma unroll
    for (int k = 0; k < 8; ++k) wred[wv][k] = q[k];
  __syncthreads();
  if (tid == 0) {
    float c0 = bias[0];
#pragma unroll
    for (int w = 0; w < 4; ++w) {
      float Sw = wred[0][w] + wred[1][w] + wred[2][w] + wred[3][w];
      float Qw = wred[0][4 + w] + wred[1][4 + w] + wred[2][4 + w] + wred[3][4 + w];
      float mu = Sw * invB;
      float var = Qw * invB - mu * mu;
      float inv = rsqrtf(var + 1e-5f);
      coefs[w] = W[w] * gamma[w] * inv;
      c0 += W[w] * (beta[w] - gamma[w] * mu * inv);
    }
    coefs[4] = c0;
  }
  __syncthreads();

  long long b = (long long)blockIdx.x * 256 + tid;
  if (b >= B) return;
  float ez[4] = {0.f, 0.f, 0.f, 0.f};
  if (useEz) {
    float4 e = ((const float4*)ez_in)[b];
    ez[0] = e.x; ez[1] = e.y; ez[2] = e.z; ez[3] = e.w;
  } else {
    float t01x[4], t01y[4], t23x[4], t23y[4];
    phase1(features, b, t01x, t01y, t23x, t23y);
    phase2_pk(U4, t01x, t01y, t23x, t23y, ez);  // U visible post-dispatch
  }
  out[b] = coefs[4] + coefs[0] * ez[0] + coefs[1] * ez[1] +
           coefs[2] * ez[2] + coefs[3] * ez[3];
}

// ================================ launch ====================================
extern "C" void kernel_launch(void* const* d_in, const int* in_sizes, int n_in,
                              void* d_out, int out_size, void* d_ws, size_t ws_size,
                              hipStream_t stream) {
  const float* features    = (const float*)d_in[0];
  const float* rand_params = (const float*)d_in[1];
  const float* rx0         = (const float*)d_in[2];
  const float* ry0         = (const float*)d_in[3];
  const float* rz0         = (const float*)d_in[4];
  const float* crx0        = (const float*)d_in[5];
  const float* gamma       = (const float*)d_in[6];
  const float* beta        = (const float*)d_in[7];
  const float* W           = (const float*)d_in[8];
  const float* bias        = (const float*)d_in[9];
  float* out = (float*)d_out;

  int B = in_sizes[0] / 16;
  int nblk = (B + 255) / 256;   // element blocks; K_B launches nblk+1

  char* ws = (char*)d_ws;
  float* Uws = (float*)ws;                        // U: 512 floats = 2048 B
  // flags: 64 copies, 128B stride, at [2048, 10240)
  float* partials = (float*)(ws + 10240);         // nblk*32 B
  size_t ez_off = (10240 + (size_t)nblk * 32 + 255) & ~(size_t)255;
  float* ez = (float*)(ws + ez_off);
  int useEz = (ws_size >= ez_off + (size_t)B * 16) ? 1 : 0;

  main_kernel<<<nblk + 1, 256, 0, stream>>>(
      features, rand_params, rx0, ry0, rz0, crx0, Uws, ez, partials, B, useEz);
  out_kernel<<<nblk, 256, 0, stream>>>(partials, nblk, gamma, beta, W, bias,
                                       ez, features, (const float4*)Uws, out,
                                       B, useEz, 1.0f / (float)B);
}

// Round 16
// 21.050 us; speedup vs baseline: 1.3793x; 1.0019x over previous
//
#include <hip/hip_runtime.h>
#include <hip/hip_fp16.h>
#include <math.h>

// ---------------------------------------------------------------------------
// FraudDetectionHybrid: 4-qubit statevector sim, algebraically collapsed.
// TWO kernels (R15 skeleton):
//   K_B (513 blk): block 0 = BUILDER (constexpr-MT19937(42) gate chunks by 4
//       waves + 2 LDS combine matmuls -> U via relaxed agent atomics + vmcnt
//       + 64 release-flag copies). Blocks 1..512: phase1 + sv/nv (hides
//       build), poll flag, U->LDS (atomic loads), pk matvec, ez(fp16x4) +
//       f32 block partials. Replay-safe: stale MAGIC benign (U bit-identical).
//   K_C (512 blk): redundant partial reduce -> BN+Linear coefs -> out
//       (reads fp16 ez; stats from exact f32 partials).
//
// R14/R15 calibration: K_B(warm)=6.5us, gap~0.55us, and profiled durations
// are inflated (main_kernel 46-49us profiled vs ~7us real) -> R6's "fixed
// ~4.8us" was bogus; fixed graph overhead F ~ 10-12us. Of 21.1us only ~9 is
// kernel time. This round: fp16 ez round-trip (saves ~2MB traffic) + sv/nv
// hoisted above the flag wait.
// History: R1-R3 scratch fixes; R5-R8 grid barriers lose to dispatch
// boundaries; R9/R10 native trig + uniform U; R11/R13 TLP null (waves/SIMD
// fixed at 2 by B); R12 pk matvec -1.6us; R15 builder-fusion -1.5us.
// ---------------------------------------------------------------------------

#define MAGIC 0x5CA1AB1Eu
#define RLX __ATOMIC_RELAXED
#define ACQ __ATOMIC_ACQUIRE
#define REL __ATOMIC_RELEASE
#define AGT __HIP_MEMORY_SCOPE_AGENT

// ==================== compile-time numpy RandomState(42) ====================
struct CGates {
  int kind[64];   // 0=RX 1=RY 2=RZ 3=CNOT 4=CRX 5=H 6=SX
  int w0[64];
  int w1[64];
  int pidx[64];   // >=0: rand_params idx; -1 none; -2 rx0; -3 ry0; -4 rz0; -5 crx0
  int ng;
};

constexpr unsigned int c_mt_next(unsigned int (&mt)[624], int& pos) {
  if (pos >= 624) {
    for (int i = 0; i < 624; ++i) {
      unsigned int y = (mt[i] & 0x80000000u) | (mt[(i + 1) % 624] & 0x7fffffffu);
      unsigned int v = mt[(i + 397) % 624] ^ (y >> 1);
      if (y & 1u) v ^= 0x9908b0dfu;
      mt[i] = v;
    }
    pos = 0;
  }
  unsigned int y = mt[pos++];
  y ^= y >> 11;
  y ^= (y << 7) & 0x9d2c5680u;
  y ^= (y << 15) & 0xefc60000u;
  y ^= y >> 18;
  return y;
}

constexpr CGates make_gates() {
  CGates gl{};
  unsigned int mt[624] = {};
  mt[0] = 42u;
  for (int i = 1; i < 624; ++i)
    mt[i] = 1812433253u * (mt[i - 1] ^ (mt[i - 1] >> 30)) + (unsigned int)i;
  int pos = 624;
  int ng = 0, p = 0;
  for (int op = 0; op < 50; ++op) {
    unsigned int k = c_mt_next(mt, pos) & 3u;   // randint(4): one draw, mask 3
    if (k < 3u) {
      unsigned int w = c_mt_next(mt, pos) & 3u; // wire
      gl.kind[ng] = (int)k; gl.w0[ng] = (int)w; gl.w1[ng] = 0;
      gl.pidx[ng] = p++;
      ++ng;
    } else {
      // choice(4,2,replace=False): Fisher-Yates descending, mask-rejection
      int arr[4] = {0, 1, 2, 3};
      { unsigned int j = c_mt_next(mt, pos) & 3u;
        int t = arr[3]; arr[3] = arr[j]; arr[j] = t; }
      { unsigned int j = c_mt_next(mt, pos) & 3u;
        while (j > 2u) j = c_mt_next(mt, pos) & 3u;
        int t = arr[2]; arr[2] = arr[j]; arr[j] = t; }
      { unsigned int j = c_mt_next(mt, pos) & 1u;
        int t = arr[1]; arr[1] = arr[j]; arr[j] = t; }
      gl.kind[ng] = 3; gl.w0[ng] = arr[0]; gl.w1[ng] = arr[1]; gl.pidx[ng] = -1;
      ++ng;
    }
  }
  // trainable block
  gl.kind[ng] = 0; gl.w0[ng] = 0; gl.w1[ng] = 0; gl.pidx[ng] = -2; ++ng; // RX w0
  gl.kind[ng] = 1; gl.w0[ng] = 1; gl.w1[ng] = 0; gl.pidx[ng] = -3; ++ng; // RY w1
  gl.kind[ng] = 2; gl.w0[ng] = 3; gl.w1[ng] = 0; gl.pidx[ng] = -4; ++ng; // RZ w3
  gl.kind[ng] = 4; gl.w0[ng] = 0; gl.w1[ng] = 2; gl.pidx[ng] = -5; ++ng; // CRX(0,2)
  gl.kind[ng] = 5; gl.w0[ng] = 3; gl.w1[ng] = 0; gl.pidx[ng] = -1; ++ng; // H w3
  gl.kind[ng] = 6; gl.w0[ng] = 2; gl.w1[ng] = 0; gl.pidx[ng] = -1; ++ng; // SX w2
  gl.kind[ng] = 3; gl.w0[ng] = 3; gl.w1[ng] = 0; gl.pidx[ng] = -1; ++ng; // CNOT(3,0)
  gl.ng = ng;
  return gl;
}

inline constexpr CGates GL = make_gates();

inline constexpr int CK1 = GL.ng / 4;
inline constexpr int CK2 = GL.ng / 2;
inline constexpr int CK3 = (3 * GL.ng) / 4;

// ================= templated gate appliers (static indices) =================
// wire0 = MSB (bit 3): TB = 8 >> wire.

template <int TB>
__device__ __forceinline__ void ap_rx(float (&sx)[16], float (&sy)[16],
                                      float c, float s) {
#pragma unroll
  for (int i = 0; i < 16; ++i) {
    if (i & TB) continue;
    const int j = i | TB;
    float ax = sx[i], ay = sy[i], bx = sx[j], by = sy[j];
    sx[i] = c * ax + s * by;  sy[i] = c * ay - s * bx;
    sx[j] = c * bx + s * ay;  sy[j] = c * by - s * ax;
  }
}

template <int TB>
__device__ __forceinline__ void ap_ry(float (&sx)[16], float (&sy)[16],
                                      float c, float s) {
#pragma unroll
  for (int i = 0; i < 16; ++i) {
    if (i & TB) continue;
    const int j = i | TB;
    float ax = sx[i], ay = sy[i], bx = sx[j], by = sy[j];
    sx[i] = c * ax - s * bx;  sy[i] = c * ay - s * by;
    sx[j] = s * ax + c * bx;  sy[j] = s * ay + c * by;
  }
}

template <int TB>
__device__ __forceinline__ void ap_rz(float (&sx)[16], float (&sy)[16],
                                      float c, float s) {
#pragma unroll
  for (int i = 0; i < 16; ++i) {
    if (i & TB) continue;
    const int j = i | TB;
    float ax = sx[i], ay = sy[i], bx = sx[j], by = sy[j];
    sx[i] = c * ax + s * ay;  sy[i] = c * ay - s * ax;
    sx[j] = c * bx - s * by;  sy[j] = c * by + s * bx;
  }
}

template <int TB>
__device__ __forceinline__ void ap_h(float (&sx)[16], float (&sy)[16]) {
  const float r = 0.70710678118654752f;
#pragma unroll
  for (int i = 0; i < 16; ++i) {
    if (i & TB) continue;
    const int j = i | TB;
    float ax = sx[i], ay = sy[i], bx = sx[j], by = sy[j];
    sx[i] = r * (ax + bx);  sy[i] = r * (ay + by);
    sx[j] = r * (ax - bx);  sy[j] = r * (ay - by);
  }
}

template <int TB>
__device__ __forceinline__ void ap_sxg(float (&sx)[16], float (&sy)[16]) {
#pragma unroll
  for (int i = 0; i < 16; ++i) {
    if (i & TB) continue;
    const int j = i | TB;
    float ax = sx[i], ay = sy[i], bx = sx[j], by = sy[j];
    sx[i] = 0.5f * (ax - ay + bx + by);  sy[i] = 0.5f * (ay + ax + by - bx);
    sx[j] = 0.5f * (ax + ay + bx - by);  sy[j] = 0.5f * (ay - ax + by + bx);
  }
}

template <int CB, int TB>
__device__ __forceinline__ void ap_cnot(float (&sx)[16], float (&sy)[16]) {
#pragma unroll
  for (int i = 0; i < 16; ++i) {
    if (!(i & CB) || (i & TB)) continue;
    const int j = i | TB;
    float tx = sx[i], ty = sy[i];
    sx[i] = sx[j]; sy[i] = sy[j];
    sx[j] = tx;    sy[j] = ty;
  }
}

template <int CB, int TB>
__device__ __forceinline__ void ap_crx(float (&sx)[16], float (&sy)[16],
                                       float c, float s) {
#pragma unroll
  for (int i = 0; i < 16; ++i) {
    if (!(i & CB) || (i & TB)) continue;
    const int j = i | TB;
    float ax = sx[i], ay = sy[i], bx = sx[j], by = sy[j];
    sx[i] = c * ax + s * by;  sy[i] = c * ay - s * bx;
    sx[j] = c * bx + s * ay;  sy[j] = c * by - s * ax;
  }
}

// ============== compile-time-unrolled gate chain over [G, GEND) =============
template <int G, int GEND>
__device__ __forceinline__ void apply_range(
    float (&sx)[16], float (&sy)[16], const float* __restrict__ rp,
    const float* __restrict__ rx0, const float* __restrict__ ry0,
    const float* __restrict__ rz0, const float* __restrict__ crx0) {
  if constexpr (G < GEND) {
    constexpr int kind = GL.kind[G];
    constexpr int TB0 = 8 >> GL.w0[G];
    constexpr int TB1 = 8 >> GL.w1[G];
    constexpr int pi = GL.pidx[G];
    float c = 0.f, s = 0.f;
    if constexpr (kind == 0 || kind == 1 || kind == 2 || kind == 4) {
      float th;
      if constexpr (pi >= 0)       th = rp[pi];
      else if constexpr (pi == -2) th = rx0[0];
      else if constexpr (pi == -3) th = ry0[0];
      else if constexpr (pi == -4) th = rz0[0];
      else                         th = crx0[0];
      float h = 0.5f * th;
      s = __sinf(h);
      c = __cosf(h);
    }
    if constexpr (kind == 0)      ap_rx<TB0>(sx, sy, c, s);
    else if constexpr (kind == 1) ap_ry<TB0>(sx, sy, c, s);
    else if constexpr (kind == 2) ap_rz<TB0>(sx, sy, c, s);
    else if constexpr (kind == 3) ap_cnot<TB0, TB1>(sx, sy);
    else if constexpr (kind == 4) ap_crx<TB0, TB1>(sx, sy, c, s);
    else if constexpr (kind == 5) ap_h<TB0>(sx, sy);
    else                          ap_sxg<TB0>(sx, sy);
    apply_range<G + 1, GEND>(sx, sy, rp, rx0, ry0, rz0, crx0);
  }
}

// ===================== per-element helpers ==================================
// phase1 + sv/nv construction (no U needed): sv = state, nv = i*state rotated
__device__ __forceinline__ void phase1_svnv(const float* __restrict__ features,
                                            long long b, float2 (&sv)[16],
                                            float2 (&nv)[16]) {
  const float4* fp = (const float4*)(features + b * 16);
  float4 F0 = fp[0], F1 = fp[1], F2 = fp[2], F3 = fp[3];
  float L0[4] = {F0.x, F0.y, F0.z, F0.w};
  float L1[4] = {F1.x, F1.y, F1.z, F1.w};
  float L2[4] = {F2.x, F2.y, F2.z, F2.w};
  float L3[4] = {F3.x, F3.y, F3.z, F3.w};
  float vax[4], vay[4], vbx[4], vby[4];
#pragma unroll
  for (int w = 0; w < 4; ++w) {
    float h0 = 0.5f * L0[w], h1 = 0.5f * L1[w];
    float h2 = 0.5f * L2[w], h3 = 0.5f * L3[w];
    float s0 = __sinf(h0), c0 = __cosf(h0);
    float s1 = __sinf(h1), c1 = __cosf(h1);
    float s2 = __sinf(h2), c2 = __cosf(h2);
    float s3 = __sinf(h3), c3 = __cosf(h3);
    float ax = c0 * c1, ay = -c0 * s1;
    float bx = s0 * c1, by = s0 * s1;
    float a2x = c2 * ax + s2 * by, a2y = c2 * ay - s2 * bx;
    float b2x = s2 * ay + c2 * bx, b2y = -s2 * ax + c2 * by;
    vax[w] = c3 * a2x - s3 * b2x; vay[w] = c3 * a2y - s3 * b2y;
    vbx[w] = s3 * a2x + c3 * b2x; vby[w] = s3 * a2y + c3 * b2y;
  }
  float t01x[4], t01y[4], t23x[4], t23y[4];
  t01x[0] = vax[0] * vax[1] - vay[0] * vay[1]; t01y[0] = vax[0] * vay[1] + vay[0] * vax[1];
  t01x[1] = vax[0] * vbx[1] - vay[0] * vby[1]; t01y[1] = vax[0] * vby[1] + vay[0] * vbx[1];
  t01x[2] = vbx[0] * vax[1] - vby[0] * vay[1]; t01y[2] = vbx[0] * vay[1] + vby[0] * vax[1];
  t01x[3] = vbx[0] * vbx[1] - vby[0] * vby[1]; t01y[3] = vbx[0] * vby[1] + vby[0] * vbx[1];
  t23x[0] = vax[2] * vax[3] - vay[2] * vay[3]; t23y[0] = vax[2] * vay[3] + vay[2] * vax[3];
  t23x[1] = vax[2] * vbx[3] - vay[2] * vby[3]; t23y[1] = vax[2] * vby[3] + vay[2] * vbx[3];
  t23x[2] = vbx[2] * vax[3] - vby[2] * vay[3]; t23y[2] = vbx[2] * vay[3] + vby[2] * vax[3];
  t23x[3] = vbx[2] * vbx[3] - vby[2] * vby[3]; t23y[3] = vbx[2] * vby[3] + vby[2] * vbx[3];
#pragma unroll
  for (int i = 0; i < 16; ++i) {
    int a = i >> 2, c = i & 3;
    float sxv = t01x[a] * t23x[c] - t01y[a] * t23y[c];
    float syv = t01x[a] * t23y[c] + t01y[a] * t23x[c];
    sv[i] = make_float2(sxv, syv);
    nv[i] = make_float2(-syv, sxv);
  }
}

// matvec: PK-packed complex, compile-time row indices
__device__ __forceinline__ void matvec_pk(const float4* U4,
                                          const float2 (&sv)[16],
                                          const float2 (&nv)[16],
                                          float (&ez)[4]) {
  float e0 = 0.f, e1 = 0.f, e2 = 0.f, e3 = 0.f;
#pragma unroll
  for (int i = 0; i < 16; ++i) {
    float2 a0 = make_float2(0.f, 0.f), a1 = make_float2(0.f, 0.f);
#pragma unroll
    for (int j2 = 0; j2 < 8; j2 += 2) {
      float4 u0 = U4[i * 8 + j2];       // (re0, im0, re1, im1)
      float4 u1 = U4[i * 8 + j2 + 1];
      int j = 2 * j2;
      a0 = a0 + sv[j] * u0.x + nv[j] * u0.y + sv[j + 1] * u0.z + nv[j + 1] * u0.w;
      a1 = a1 + sv[j + 2] * u1.x + nv[j + 2] * u1.y + sv[j + 3] * u1.z +
           nv[j + 3] * u1.w;
    }
    float2 a = a0 + a1;
    float p = a.x * a.x + a.y * a.y;
    e0 += (i & 8) ? -p : p;
    e1 += (i & 4) ? -p : p;
    e2 += (i & 2) ? -p : p;
    e3 += (i & 1) ? -p : p;
  }
  ez[0] = e0; ez[1] = e1; ez[2] = e2; ez[3] = e3;
}

// ==== K_B: block 0 = builder; blocks 1..nblk = elements (flag handshake) ====
__global__ __launch_bounds__(256, 4) void main_kernel(
    const float* __restrict__ features, const float* __restrict__ rand_params,
    const float* __restrict__ rx0, const float* __restrict__ ry0,
    const float* __restrict__ rz0, const float* __restrict__ crx0,
    float* __restrict__ Uws, unsigned int* __restrict__ ez_out,
    float* __restrict__ partials, int B, int useEz) {
  __shared__ float2 chunks[4][256];   // block0: build; others: [0] = U copy
  __shared__ float2 comb[2][256];
  __shared__ float wred[4][8];
  int tid = threadIdx.x;
  int bid = blockIdx.x;
  int wv = tid >> 6, lane = tid & 63;
  unsigned int* flagbase = (unsigned int*)(Uws + 512);  // 64 flags, 128B apart

  if (bid == 0) {
    // ---- builder: 4-wave chunk build + 2 combine rounds ----
    if (lane < 16) {
      float sx[16], sy[16];
#pragma unroll
      for (int i = 0; i < 16; ++i) { sx[i] = (i == lane) ? 1.f : 0.f; sy[i] = 0.f; }
      if (wv == 0)      apply_range<0,   CK1  >(sx, sy, rand_params, rx0, ry0, rz0, crx0);
      else if (wv == 1) apply_range<CK1, CK2  >(sx, sy, rand_params, rx0, ry0, rz0, crx0);
      else if (wv == 2) apply_range<CK2, CK3  >(sx, sy, rand_params, rx0, ry0, rz0, crx0);
      else              apply_range<CK3, GL.ng>(sx, sy, rand_params, rx0, ry0, rz0, crx0);
#pragma unroll
      for (int i = 0; i < 16; ++i)
        chunks[wv][i * 16 + lane] = make_float2(sx[i], sy[i]);
    }
    __syncthreads();
    {
      int r = tid >> 4, c = tid & 15;
      float xr = 0.f, xi = 0.f, yr = 0.f, yi = 0.f;
#pragma unroll
      for (int k = 0; k < 16; ++k) {
        float2 g1 = chunks[1][r * 16 + k], g0 = chunks[0][k * 16 + c];
        xr += g1.x * g0.x - g1.y * g0.y;  xi += g1.x * g0.y + g1.y * g0.x;
        float2 g3 = chunks[3][r * 16 + k], g2 = chunks[2][k * 16 + c];
        yr += g3.x * g2.x - g3.y * g2.y;  yi += g3.x * g2.y + g3.y * g2.x;
      }
      comb[0][r * 16 + c] = make_float2(xr, xi);
      comb[1][r * 16 + c] = make_float2(yr, yi);
    }
    __syncthreads();
    {
      int r = tid >> 4, c = tid & 15;
      float ur = 0.f, ui = 0.f;
#pragma unroll
      for (int k = 0; k < 16; ++k) {
        float2 a = comb[1][r * 16 + k], d = comb[0][k * 16 + c];
        ur += a.x * d.x - a.y * d.y;
        ui += a.x * d.y + a.y * d.x;
      }
      __hip_atomic_store(&Uws[2 * tid], ur, RLX, AGT);
      __hip_atomic_store(&Uws[2 * tid + 1], ui, RLX, AGT);
    }
    asm volatile("s_waitcnt vmcnt(0)" ::: "memory");
    __syncthreads();
    if (tid < 64)
      __hip_atomic_store(&flagbase[tid * 32], MAGIC, REL, AGT);
    return;
  }

  // ---- element blocks ----
  long long b = (long long)(bid - 1) * 256 + tid;
  bool valid = b < B;
  float2 sv[16], nv[16];
  if (valid) phase1_svnv(features, b, sv, nv);   // hides U build (1st call)

  if (tid == 0) {
    unsigned int* myflag = &flagbase[(bid & 63) * 32];
    while (__hip_atomic_load(myflag, ACQ, AGT) != MAGIC)
      __builtin_amdgcn_s_sleep(2);
  }
  __syncthreads();
  {
    float* Ul = (float*)&chunks[0][0];
    Ul[tid]       = __hip_atomic_load(&Uws[tid], RLX, AGT);
    Ul[tid + 256] = __hip_atomic_load(&Uws[tid + 256], RLX, AGT);
  }
  __syncthreads();

  float ez[4] = {0.f, 0.f, 0.f, 0.f};
  if (valid) {
    matvec_pk((const float4*)&chunks[0][0], sv, nv, ez);
    if (useEz) {
      __half2 lo = __floats2half2_rn(ez[0], ez[1]);
      __half2 hi = __floats2half2_rn(ez[2], ez[3]);
      uint2 pk;
      pk.x = *(unsigned int*)&lo;
      pk.y = *(unsigned int*)&hi;
      ((uint2*)ez_out)[b] = pk;        // 8B/element fp16x4
    }
  }
  float q[8] = {ez[0], ez[1], ez[2], ez[3],
                ez[0] * ez[0], ez[1] * ez[1], ez[2] * ez[2], ez[3] * ez[3]};
#pragma unroll
  for (int off = 32; off; off >>= 1)
#pragma unroll
    for (int k = 0; k < 8; ++k) q[k] += __shfl_down(q[k], off, 64);
  if (lane == 0)
#pragma unroll
    for (int k = 0; k < 8; ++k) wred[wv][k] = q[k];
  __syncthreads();
  if (tid == 0) {
#pragma unroll
    for (int k = 0; k < 8; ++k)
      partials[(size_t)(bid - 1) * 8 + k] =
          wred[0][k] + wred[1][k] + wred[2][k] + wred[3][k];
  }
}

// ========= K_C: redundant stats reduce -> coefs -> output pass ==============
__global__ __launch_bounds__(256) void out_kernel(
    const float* __restrict__ partials, int nblk,
    const float* __restrict__ gamma, const float* __restrict__ beta,
    const float* __restrict__ W, const float* __restrict__ bias,
    const unsigned int* __restrict__ ez_in, const float* __restrict__ features,
    const float4* __restrict__ U4, float* __restrict__ out,
    int B, int useEz, float invB) {
  __shared__ float wred[4][8];
  __shared__ float coefs[5];
  int tid = threadIdx.x;

  float q[8] = {0.f, 0.f, 0.f, 0.f, 0.f, 0.f, 0.f, 0.f};
  for (int idx = tid; idx < nblk; idx += 256) {
    const float4* p4 = (const float4*)(partials + (size_t)idx * 8);
    float4 A = p4[0], Bq = p4[1];
    q[0] += A.x;  q[1] += A.y;  q[2] += A.z;  q[3] += A.w;
    q[4] += Bq.x; q[5] += Bq.y; q[6] += Bq.z; q[7] += Bq.w;
  }
#pragma unroll
  for (int off = 32; off; off >>= 1)
#pragma unroll
    for (int k = 0; k < 8; ++k) q[k] += __shfl_down(q[k], off, 64);
  int lane = tid & 63, wv = tid >> 6;
  if (lane == 0)
#pragma unroll
    for (int k = 0; k < 8; ++k) wred[wv][k] = q[k];
  __syncthreads();
  if (tid == 0) {
    float c0 = bias[0];
#pragma unroll
    for (int w = 0; w < 4; ++w) {
      float Sw = wred[0][w] + wred[1][w] + wred[2][w] + wred[3][w];
      float Qw = wred[0][4 + w] + wred[1][4 + w] + wred[2][4 + w] + wred[3][4 + w];
      float mu = Sw * invB;
      float var = Qw * invB - mu * mu;
      float inv = rsqrtf(var + 1e-5f);
      coefs[w] = W[w] * gamma[w] * inv;
      c0 += W[w] * (beta[w] - gamma[w] * mu * inv);
    }
    coefs[4] = c0;
  }
  __syncthreads();

  long long b = (long long)blockIdx.x * 256 + tid;
  if (b >= B) return;
  float ez[4] = {0.f, 0.f, 0.f, 0.f};
  if (useEz) {
    uint2 pk = ((const uint2*)ez_in)[b];
    __half2 lo = *(__half2*)&pk.x;
    __half2 hi = *(__half2*)&pk.y;
    float2 l = __half22float2(lo), h = __half22float2(hi);
    ez[0] = l.x; ez[1] = l.y; ez[2] = h.x; ez[3] = h.y;
  } else {
    float2 sv[16], nv[16];
    phase1_svnv(features, b, sv, nv);
    matvec_pk(U4, sv, nv, ez);   // U visible post-dispatch
  }
  out[b] = coefs[4] + coefs[0] * ez[0] + coefs[1] * ez[1] +
           coefs[2] * ez[2] + coefs[3] * ez[3];
}

// ================================ launch ====================================
extern "C" void kernel_launch(void* const* d_in, const int* in_sizes, int n_in,
                              void* d_out, int out_size, void* d_ws, size_t ws_size,
                              hipStream_t stream) {
  const float* features    = (const float*)d_in[0];
  const float* rand_params = (const float*)d_in[1];
  const float* rx0         = (const float*)d_in[2];
  const float* ry0         = (const float*)d_in[3];
  const float* rz0         = (const float*)d_in[4];
  const float* crx0        = (const float*)d_in[5];
  const float* gamma       = (const float*)d_in[6];
  const float* beta        = (const float*)d_in[7];
  const float* W           = (const float*)d_in[8];
  const float* bias        = (const float*)d_in[9];
  float* out = (float*)d_out;

  int B = in_sizes[0] / 16;
  int nblk = (B + 255) / 256;   // element blocks; K_B launches nblk+1

  char* ws = (char*)d_ws;
  float* Uws = (float*)ws;                        // U: 512 floats = 2048 B
  // flags: 64 copies, 128B stride, at [2048, 10240)
  float* partials = (float*)(ws + 10240);         // nblk*32 B
  size_t ez_off = (10240 + (size_t)nblk * 32 + 255) & ~(size_t)255;
  unsigned int* ez = (unsigned int*)(ws + ez_off);
  int useEz = (ws_size >= ez_off + (size_t)B * 8) ? 1 : 0;

  main_kernel<<<nblk + 1, 256, 0, stream>>>(
      features, rand_params, rx0, ry0, rz0, crx0, Uws, ez, partials, B, useEz);
  out_kernel<<<nblk, 256, 0, stream>>>(partials, nblk, gamma, beta, W, bias,
                                       ez, features, (const float4*)Uws, out,
                                       B, useEz, 1.0f / (float)B);
}